// Round 4
// baseline (151.073 us; speedup 1.0000x reference)
//
#include <hip/hip_runtime.h>

// Problem constants
#define MD 4
#define DD 9            // 2*MD+1
#define B  4
#define C  64
#define H  64
#define W  128
#define HW (H * W)      // 8192 floats per (i,j) slice of one (b,c)

typedef float f32x4 __attribute__((ext_vector_type(4)));

// out[b][c][i][j][y][x] = leaky_relu(ref[b,c,y,x] * tgt[b,c, y+j-4, x+i-4]), 0 OOB.
//
// Block = one (bc, i) unit, i a COMPILE-TIME template param (d = i-4 static):
//   - thread preloads its 8 ref float4s into registers (one per 8-row stripe)
//   - per (j, s): 1-2 aligned tgt float4 loads (L2-hot) + static register pick
//     of the d-shifted window + 1 nontemporal float4 store
//   - stores march linearly through the unit's 288 KB contiguous output
//   - no LDS, no barriers -> store pipe never drains (lesson from round 3)
// OOB columns: lane x4==0 zeroes its m-vector (d<0), lane x4==31 zeroes its
// p-vector (d>0) -- exactly the elements that would index cols <0 / >=W.
// OOB rows: clamp row address (stays in-plane), select 0 after.

template<int I>
__device__ __forceinline__ void run_i(const float* __restrict__ refp,
                                      const float* __restrict__ tgtp,
                                      float* __restrict__ outp,   // + (bc*81 + I*9)*HW
                                      unsigned t) {
    constexpr int d = I - MD;   // -4..4
    const unsigned x4 = t & 31u;
    const unsigned yw = t >> 5;     // 0..7
    const unsigned x  = x4 * 4u;

    // 8 ref float4s: rows yw, 8+yw, ..., 56+yw
    f32x4 r8[8];
    #pragma unroll
    for (int s = 0; s < 8; ++s)
        r8[s] = *reinterpret_cast<const f32x4*>(refp + (unsigned)(s * 8 + yw) * W + x);

    #pragma unroll
    for (int j = 0; j < DD; ++j) {
        float* oj = outp + (size_t)j * HW;
        #pragma unroll
        for (int s = 0; s < 8; ++s) {
            const int y  = s * 8 + (int)yw;
            const int ty = y + j - MD;
            const bool vrow = (ty >= 0) & (ty < H);
            const int tyc = ty < 0 ? 0 : (ty > H - 1 ? H - 1 : ty);
            const float* trow = tgtp + (unsigned)tyc * W;

            f32x4 m = {0.f, 0.f, 0.f, 0.f};
            f32x4 c;
            f32x4 p = {0.f, 0.f, 0.f, 0.f};
            if constexpr (d < 0) {
                if (x4 > 0) m = *reinterpret_cast<const f32x4*>(trow + x - 4);
            }
            c = *reinterpret_cast<const f32x4*>(trow + x);
            if constexpr (d > 0) {
                if (x4 < 31u) p = *reinterpret_cast<const f32x4*>(trow + x + 4);
            }
            // 12-float window; all indices static after unroll -> registers
            const float tw[12] = {m.x, m.y, m.z, m.w,
                                  c.x, c.y, c.z, c.w,
                                  p.x, p.y, p.z, p.w};
            f32x4 o;
            #pragma unroll
            for (int e = 0; e < 4; ++e) {
                const float wv = tw[4 + d + e];     // static index
                float pv = r8[s][e] * wv;
                pv = fmaxf(pv, 0.1f * pv);          // leaky_relu
                o[e] = vrow ? pv : 0.0f;
            }
            __builtin_nontemporal_store(
                o, reinterpret_cast<f32x4*>(oj + (unsigned)y * W + x));
        }
    }
}

__global__ __launch_bounds__(256) void corr_kernel(const float* __restrict__ ref,
                                                   const float* __restrict__ tgt,
                                                   float* __restrict__ out) {
    const unsigned blk = blockIdx.x;
    const unsigned bc  = blk / 9u;        // magic-mul
    const unsigned i   = blk - bc * 9u;

    const float* refp = ref + (size_t)bc * HW;
    const float* tgtp = tgt + (size_t)bc * HW;
    float* outp = out + ((size_t)bc * (DD * DD) + (size_t)i * DD) * HW;
    const unsigned t = threadIdx.x;

    switch (i) {
        case 0: run_i<0>(refp, tgtp, outp, t); break;
        case 1: run_i<1>(refp, tgtp, outp, t); break;
        case 2: run_i<2>(refp, tgtp, outp, t); break;
        case 3: run_i<3>(refp, tgtp, outp, t); break;
        case 4: run_i<4>(refp, tgtp, outp, t); break;
        case 5: run_i<5>(refp, tgtp, outp, t); break;
        case 6: run_i<6>(refp, tgtp, outp, t); break;
        case 7: run_i<7>(refp, tgtp, outp, t); break;
        default: run_i<8>(refp, tgtp, outp, t); break;
    }
}

extern "C" void kernel_launch(void* const* d_in, const int* in_sizes, int n_in,
                              void* d_out, int out_size, void* d_ws, size_t ws_size,
                              hipStream_t stream) {
    const float* ref = (const float*)d_in[0];
    const float* tgt = (const float*)d_in[1];
    float* out = (float*)d_out;

    // 256 bc-planes x 9 i-values = 2304 blocks, each writing one contiguous
    // 288 KB output unit. No LDS, no barriers.
    corr_kernel<<<B * C * DD, 256, 0, stream>>>(ref, tgt, out);
}

// Round 5
// 134.895 us; speedup vs baseline: 1.1199x; 1.1199x over previous
//
#include <hip/hip_runtime.h>

// Problem constants
#define MD 4
#define DD 9          // 2*MD+1
#define B  4
#define C  64
#define H  64
#define W  128
#define W4 (W / 4)    // 32 float4 per row
#define HW (H * W)    // 8192 floats per (i,j) slice of one (b,c)

typedef float f32x4 __attribute__((ext_vector_type(4)));

// Round-2 structure (best so far: 136.7 us), single variable changed:
// PLAIN stores instead of __builtin_nontemporal_store (A/B the nt flag).
// out[b][c][i][j][y][x] = leaky_relu(ref[b,c,y,x] * tgt[b,c, y+j-4, x+i-4]), 0 OOB.
// One thread per (b,c,y,x4): ref f4 in register; per j, 12-float tgt window
// via 3 aligned f4 loads (edge vectors zeroed branch-free); 9 shifted
// products -> 9 f4 stores. 2048 blocks = 8/CU, full occupancy, no LDS.

__device__ __forceinline__ float lrelu(float p) {
    return fmaxf(p, 0.1f * p);
}

__global__ __launch_bounds__(256) void corr_kernel(const float* __restrict__ ref,
                                                   const float* __restrict__ tgt,
                                                   float* __restrict__ out) {
    const unsigned bc = blockIdx.x >> 3;          // 0..255
    const unsigned yg = blockIdx.x & 7;           // 0..7
    const unsigned x4 = threadIdx.x & 31;         // 0..31
    const unsigned y  = yg * 8 + (threadIdx.x >> 5);
    const unsigned x  = x4 * 4;

    const f32x4 r = *reinterpret_cast<const f32x4*>(ref + ((size_t)bc * H + y) * W + x);

    float* const out_base = out + (size_t)bc * (DD * DD * HW) + (size_t)y * W + x;
    const float* const tgt_bc = tgt + (size_t)bc * HW;

    const bool has_m = (x4 > 0);
    const bool has_p = (x4 < W4 - 1);

    #pragma unroll
    for (int j = 0; j < DD; ++j) {
        const int ty = (int)y + j - MD;
        const bool vrow = (ty >= 0) & (ty < H);
        const int tyc = ty < 0 ? 0 : (ty > H - 1 ? H - 1 : ty);
        const float* trow = tgt_bc + (size_t)tyc * W;

        // Branch-free: clamp edge addresses in-row, zero-select after.
        f32x4 tm = *reinterpret_cast<const f32x4*>(trow + (has_m ? x - 4 : x));
        f32x4 tc = *reinterpret_cast<const f32x4*>(trow + x);
        f32x4 tp = *reinterpret_cast<const f32x4*>(trow + (has_p ? x + 4 : x));
        const float zm = (vrow & has_m) ? 1.f : 0.f;
        const float zc = vrow ? 1.f : 0.f;
        const float zp = (vrow & has_p) ? 1.f : 0.f;
        tm *= zm; tc *= zc; tp *= zp;

        const float t[12] = {tm.x, tm.y, tm.z, tm.w,
                             tc.x, tc.y, tc.z, tc.w,
                             tp.x, tp.y, tp.z, tp.w};

        float* op = out_base + (size_t)j * HW;
        #pragma unroll
        for (int i = 0; i < DD; ++i) {
            f32x4 o;
            o.x = lrelu(r.x * t[i + 0]);
            o.y = lrelu(r.y * t[i + 1]);
            o.z = lrelu(r.z * t[i + 2]);
            o.w = lrelu(r.w * t[i + 3]);
            *reinterpret_cast<f32x4*>(op) = o;      // PLAIN store (A/B vs nt)
            op += (size_t)DD * HW;
        }
    }
}

extern "C" void kernel_launch(void* const* d_in, const int* in_sizes, int n_in,
                              void* d_out, int out_size, void* d_ws, size_t ws_size,
                              hipStream_t stream) {
    const float* ref = (const float*)d_in[0];
    const float* tgt = (const float*)d_in[1];
    float* out = (float*)d_out;

    const unsigned blocks = B * C * (H / 8);  // 2048
    corr_kernel<<<blocks, 256, 0, stream>>>(ref, tgt, out);
}

// Round 6
// 131.411 us; speedup vs baseline: 1.1496x; 1.0265x over previous
//
#include <hip/hip_runtime.h>

// Problem constants
#define MD 4
#define DD 9          // 2*MD+1
#define B  4
#define C  64
#define H  64
#define W  128
#define W4 (W / 4)    // 32 float4 per row
#define HW (H * W)    // 8192 floats per (i,j) slice of one (b,c)

typedef float f32x4 __attribute__((ext_vector_type(4)));

// out[b][c][i][j][y][x] = leaky_relu(ref[b,c,y,x]*tgt[b,c,y+j-4,x+i-4]), 0 OOB.
//
// Round-6 hypothesis: loads and stores share vmcnt; interleaving
// {load window -> use -> store x9} forces a store-queue drain every j.
// Fix: LOAD EVERYTHING FIRST (one waitcnt with zero stores outstanding),
// then a pure store burst with no waitcnt at all (fill-kernel behavior).
// j-range split across 2 blocks so the window fits registers:
//   jh=0: j=0..4  -> window rows ty=y-4..y   (15 f4 loads, 45 stores)
//   jh=1: j=5..8  -> window rows ty=y+1..y+4 (12 f4 loads, 36 stores)

__device__ __forceinline__ float lrelu(float p) {
    return fmaxf(p, 0.1f * p);
}

template<int JSTART, int JCNT>
__device__ __forceinline__ void run_half(const float* __restrict__ refp,
                                         const float* __restrict__ tgtp,
                                         float* __restrict__ outb,  // + bc*81*HW
                                         unsigned y, unsigned x4) {
    const unsigned x = x4 * 4u;
    const bool has_m = (x4 > 0);
    const bool has_p = (x4 < W4 - 1);

    const f32x4 r = *reinterpret_cast<const f32x4*>(refp + (size_t)y * W + x);

    // ---- load phase: entire window into registers, zero-masked ----
    f32x4 win[JCNT][3];
    #pragma unroll
    for (int rr = 0; rr < JCNT; ++rr) {
        const int ty = (int)y + (JSTART + rr) - MD;
        const bool vrow = (ty >= 0) & (ty < H);
        const int tyc = ty < 0 ? 0 : (ty > H - 1 ? H - 1 : ty);
        const float* trow = tgtp + (size_t)tyc * W;
        f32x4 tm = *reinterpret_cast<const f32x4*>(trow + (has_m ? x - 4 : x));
        f32x4 tc = *reinterpret_cast<const f32x4*>(trow + x);
        f32x4 tp = *reinterpret_cast<const f32x4*>(trow + (has_p ? x + 4 : x));
        const float zm = (vrow & has_m) ? 1.f : 0.f;
        const float zc = vrow ? 1.f : 0.f;
        const float zp = (vrow & has_p) ? 1.f : 0.f;
        win[rr][0] = tm * zm;
        win[rr][1] = tc * zc;
        win[rr][2] = tp * zp;
    }

    // ---- store phase: pure burst, no loads, no waitcnt ----
    #pragma unroll
    for (int rr = 0; rr < JCNT; ++rr) {
        const int j = JSTART + rr;
        const float tw[12] = {win[rr][0].x, win[rr][0].y, win[rr][0].z, win[rr][0].w,
                              win[rr][1].x, win[rr][1].y, win[rr][1].z, win[rr][1].w,
                              win[rr][2].x, win[rr][2].y, win[rr][2].z, win[rr][2].w};
        #pragma unroll
        for (int i = 0; i < DD; ++i) {
            f32x4 o;
            o.x = lrelu(r.x * tw[i + 0]);
            o.y = lrelu(r.y * tw[i + 1]);
            o.z = lrelu(r.z * tw[i + 2]);
            o.w = lrelu(r.w * tw[i + 3]);
            *reinterpret_cast<f32x4*>(
                outb + (size_t)(i * DD + j) * HW + (size_t)y * W + x) = o;
        }
    }
}

__global__ __launch_bounds__(256) void corr_kernel(const float* __restrict__ ref,
                                                   const float* __restrict__ tgt,
                                                   float* __restrict__ out) {
    // grid = bc(256) * ysplit(8) * jhalf(2) = 4096 blocks
    const unsigned blk = blockIdx.x;
    const unsigned jh  = blk & 1u;
    const unsigned ysp = (blk >> 1) & 7u;
    const unsigned bc  = blk >> 4;

    const unsigned x4 = threadIdx.x & 31u;
    const unsigned y  = ysp * 8u + (threadIdx.x >> 5);

    const float* refp = ref + (size_t)bc * HW;
    const float* tgtp = tgt + (size_t)bc * HW;
    float* outb = out + (size_t)bc * (DD * DD * HW);

    if (jh == 0) run_half<0, 5>(refp, tgtp, outb, y, x4);
    else         run_half<5, 4>(refp, tgtp, outb, y, x4);
}

extern "C" void kernel_launch(void* const* d_in, const int* in_sizes, int n_in,
                              void* d_out, int out_size, void* d_ws, size_t ws_size,
                              hipStream_t stream) {
    const float* ref = (const float*)d_in[0];
    const float* tgt = (const float*)d_in[1];
    float* out = (float*)d_out;

    corr_kernel<<<B * C * 8 * 2, 256, 0, stream>>>(ref, tgt, out);
}